// Round 4
// baseline (128.018 us; speedup 1.0000x reference)
//
#include <hip/hip_runtime.h>
#include <cstdint>

// Shapes fixed by the harness:
// u, delta, z: (b=2, d=1024, l=2048) fp32; A: (d, n=16); B, C: (b, n, l); D: (d,)
constexpr int kD = 1024;
constexpr int kN = 16;
constexpr int kL = 2048;
constexpr int BLOCK = 512;
constexpr int T  = kL / BLOCK;   // 4 timesteps per thread (one float4)
constexpr int NW = BLOCK / 64;   // 8 waves per block
constexpr int NQ = 4;            // states per pass (quarter of kN)
constexpr int NP = kN / NQ;      // 4 passes
constexpr float LOG2E = 1.44269504088896340736f;

// s_waitcnt immediates (gfx9 encoding: vm[3:0]+[15:14], exp[6:4], lgkm[11:8])
constexpr unsigned WAIT_LGKM0 = 0xC07F;  // lgkmcnt(0); vmcnt/expcnt = no-wait
constexpr unsigned WAIT_VM5   = 0x0F75;  // vmcnt(5);   lgkm/expcnt  = no-wait

__device__ __forceinline__ float fast_exp2(float x) { return __builtin_amdgcn_exp2f(x); }
__device__ __forceinline__ float fast_exp(float x)  { return __builtin_amdgcn_exp2f(x * LOG2E); }
__device__ __forceinline__ float softplus_f(float x) {
  return (x > 20.0f) ? x : __logf(1.0f + fast_exp(x));
}

// Async global->LDS (16B/lane). Each thread stages ITS OWN float4 into its own
// LDS slot (dest = wave-uniform base + lane*16; lane0's pointer IS the wave
// base, so passing the per-lane slot pointer is correct). Self-staged,
// self-read => ordering is purely this wave's vmcnt: NO barrier, NO dbuf.
__device__ __forceinline__ void stage16(const float* g, float* l) {
  __builtin_amdgcn_global_load_lds(
      (const __attribute__((address_space(1))) void*)g,
      (__attribute__((address_space(3))) void*)l, 16, 0, 0);
}

// DPP move with explicit 'old' (identity) — used only for the lane-exclusive
// prefix in the apply phase.
template<int CTRL, int RM>
__device__ __forceinline__ float dppf(float old_, float src) {
  union U { float f; int i; };
  U o, s, r; o.f = old_; s.f = src;
  r.i = __builtin_amdgcn_update_dpp(o.i, s.i, CTRL, RM, 0xF, false);
  return r.f;
}

__device__ __forceinline__ float readlane_f(float v, int l) {
  union U { float f; int i; };
  U a, r; a.f = v;
  r.i = __builtin_amdgcn_readlane(a.i, l);
  return r.f;
}

// R12: hot 64-lane scan in raw DPP asm. bound_ctrl off + row_mask => invalid
// lanes DON'T WRITE dest, so in-place
//   v_fmac_f32_dpp x, x, a   (x += dpp(x)*a; boundary lanes keep x)
//   v_mul_f32_dpp  a, a, a   (a *= dpp(a);   boundary lanes keep a)
// is one masked Hillis-Steele step in 2 insts/state. State-inner interleave
// gives 8-inst spacing for the VALU->DPP hazard; s_nop 1 covers entry.
#define SCAN_FM(X, A, CTRL) \
  "v_fmac_f32_dpp " X ", " X ", " A " " CTRL "\n\t" \
  "v_mul_f32_dpp "  A ", " A ", " A " " CTRL "\n\t"
#define SCAN_STEP(CTRL) \
  SCAN_FM("%0","%4",CTRL) SCAN_FM("%1","%5",CTRL) \
  SCAN_FM("%2","%6",CTRL) SCAN_FM("%3","%7",CTRL)

// One selective-scan step for element i of a state: a = exp2(spl*A);
// h = a*h + du*B; p *= a; y += C*h; cp = C*p. Direct float4 components
// (no Bv[]/Cv[] staging arrays -> no chance of stray v_movs).
#define SSTEP(i, Bc, Cc) {                         \
    float a_ = fast_exp2(spl[i] * Arn);            \
    h = fmaf(a_, h, du[i] * (Bc));                 \
    p *= a_;                                       \
    y[i] = fmaf((Cc), h, y[i]);                    \
    cp[n][i] = (Cc) * p; }

// Single-arg launch_bounds ONLY: any min-waves hint triggers a spill cascade
// (R2: 48 VGPR + 350 MB scratch; R3: 64 VGPR + 260 MB; R6: 1024-thr cap).
// Occupancy raised STRUCTURALLY (R2 of this session): 4 passes of 4 states
// crossed the <=64-VGPR cliff -> 8 waves/SIMD, 4 blocks/CU. Keep VGPR <= 64!
__global__ __launch_bounds__(BLOCK)
void selscan_kernel(const float* __restrict__ u,  const float* __restrict__ dl,
                    const float* __restrict__ A,  const float* __restrict__ Bm,
                    const float* __restrict__ Cm, const float* __restrict__ Dv,
                    const float* __restrict__ zm, float* __restrict__ out)
{
  const int row  = blockIdx.x;          // b*kD + d
  const int b    = row >> 10;           // kD = 1024
  const int d    = row & (kD - 1);
  const int tid  = threadIdx.x;
  const int lane = tid & 63;
  const int wid  = tid >> 6;

  const size_t roff = (size_t)row * kL;
  const float4* u4 = reinterpret_cast<const float4*>(u  + roff);
  const float4* d4 = reinterpret_cast<const float4*>(dl + roff);
  const float4* B4all = reinterpret_cast<const float4*>(Bm + (size_t)b * kN * kL);
  const float4* C4all = reinterpret_cast<const float4*>(Cm + (size_t)b * kN * kL);
  const float4* A4row = reinterpret_cast<const float4*>(A + (size_t)d * kN);

  // Staging buffer for each pass's FIRST TWO states' B/C tiles:
  // [B/C][state-in-pair][tid]. 32 KB/block; +sAX => 33 KB -> 4 blocks/CU.
  // Single-buffered: this thread's ds_reads retire (lgkmcnt(0)) before the
  // next DMA to the same slots is issued; each thread touches only its own
  // slot, so there is no cross-wave hazard.
  __shared__ float4 stg[2][2][BLOCK];
  // Per-pass wave-total buffers: (a,x) per (wave, state). 4*8*4*8B = 1 KB.
  __shared__ float2 sAX[NP][NW][NQ];

  // Prologue issue order (vm queue): u, d, A0, DMA*4.
  // softplus waits u,d (compiler, counted); at pass-0 top the outstanding
  // set is then [A0, DMA*4] — the SAME shape as steady state [A_q, DMA*4],
  // so one uniform vmcnt(5) works for every pass.
  float4 a0 = u4[tid];
  float4 b0_ = d4[tid];
  float4 Acur = A4row[0];
  stage16((const float*)&B4all[0 * (kL/4) + tid], (float*)&stg[0][0][tid]);
  stage16((const float*)&B4all[1 * (kL/4) + tid], (float*)&stg[0][1][tid]);
  stage16((const float*)&C4all[0 * (kL/4) + tid], (float*)&stg[1][0][tid]);
  stage16((const float*)&C4all[1 * (kL/4) + tid], (float*)&stg[1][1][tid]);

  // Per-thread chunk [tid*T, tid*T+T): softplus(delta)*LOG2E and delta*u in
  // regs. u itself is NOT carried — re-loaded in the epilogue.
  float spl[T], du[T];
  {
    float uv[T] = {a0.x, a0.y, a0.z, a0.w};
    float dv[T] = {b0_.x, b0_.y, b0_.z, b0_.w};
    #pragma unroll
    for (int i = 0; i < T; ++i) {
      float s = softplus_f(dv[i]);
      du[i]  = s * uv[i];
      spl[i] = s * LOG2E;              // exp2 arg = spl*A == sp*LOG2E*A
    }
  }

  float y[T];
  #pragma unroll
  for (int i = 0; i < T; ++i) y[i] = 0.0f;

  #pragma unroll 1                      // passes sequential: live-range control
  for (int q = 0; q < NP; ++q) {
    const float4* Bq = B4all + (size_t)(q * NQ) * (kL/4);
    const float4* Cq = C4all + (size_t)(q * NQ) * (kL/4);

    // ---- Issue group (5 vm ops, ABOVE the wait so their latency overlaps
    // the DMA drain): this pass's pair-1 globals + NEXT pass's A row.
    // qn is clamped (q=3 reloads A3, dead) so the vm-op count is uniform
    // and vmcnt(5) is exact in every pass.
    const int qn = (q + 1 < NP) ? q + 1 : NP - 1;
    float4 b2 = Bq[2 * (kL/4) + tid];
    float4 c2 = Cq[2 * (kL/4) + tid];
    float4 b3 = Bq[3 * (kL/4) + tid];
    float4 c3 = Cq[3 * (kL/4) + tid];
    float4 An = A4row[qn];
    __builtin_amdgcn_sched_barrier(0);   // pin the 5 issues above the wait

    // Drain exactly [A_q, DMA*4] (the 5 oldest); the 5 just-issued stay in
    // flight. NEVER vmcnt(0) here — that would serialize pair-1's latency.
    __builtin_amdgcn_s_waitcnt(WAIT_VM5);
    __builtin_amdgcn_sched_barrier(0);   // pin ds_reads below the wait

    // Staged pair-0: data has been in LDS since its DMA (issued a full pass
    // ago) completed. 16B/lane stride: conflict-free ds_read_b128.
    float4 b0 = stg[0][0][tid];
    float4 b1 = stg[0][1][tid];
    float4 c0 = stg[1][0][tid];
    float4 c1 = stg[1][1][tid];
    __builtin_amdgcn_s_waitcnt(WAIT_LGKM0);  // reads retired -> slots reusable
    __builtin_amdgcn_sched_barrier(0);       // rule 18: pin uses below

    // ---- NEXT pass's pair-0 DMAs issued at the TOP: they get the whole
    // pass body (compute+scan+barrier+fold+apply, ~500-700 cy) of cover.
    // (R3 issued them after the scan — only ~150 cy of cover — and was flat.)
    if (q < NP - 1) {
      const float4* Bn = B4all + (size_t)((q + 1) * NQ) * (kL/4);
      const float4* Cn = C4all + (size_t)((q + 1) * NQ) * (kL/4);
      stage16((const float*)&Bn[0 * (kL/4) + tid], (float*)&stg[0][0][tid]);
      stage16((const float*)&Bn[1 * (kL/4) + tid], (float*)&stg[0][1][tid]);
      stage16((const float*)&Cn[0 * (kL/4) + tid], (float*)&stg[1][0][tid]);
      stage16((const float*)&Cn[1 * (kL/4) + tid], (float*)&stg[1][1][tid]);
    }

    // ---- Pass A with the cp-trick: C consumed at load time.
    // h_i = pp_i*h0 + hl_i (linearity) =>  y_i += C_i*hl_i here,
    // cp_i = C_i*pp_i saved; post-scan apply is pure register FMA.
    float cp[NQ][T];
    float cA[NQ], cX[NQ];
    {
      { const int n = 0; const float Arn = Acur.x; float h = 0.f, p = 1.f;
        SSTEP(0, b0.x, c0.x) SSTEP(1, b0.y, c0.y) SSTEP(2, b0.z, c0.z) SSTEP(3, b0.w, c0.w)
        cA[n] = p; cX[n] = h; }
      { const int n = 1; const float Arn = Acur.y; float h = 0.f, p = 1.f;
        SSTEP(0, b1.x, c1.x) SSTEP(1, b1.y, c1.y) SSTEP(2, b1.z, c1.z) SSTEP(3, b1.w, c1.w)
        cA[n] = p; cX[n] = h; }
      { const int n = 2; const float Arn = Acur.z; float h = 0.f, p = 1.f;
        SSTEP(0, b2.x, c2.x) SSTEP(1, b2.y, c2.y) SSTEP(2, b2.z, c2.z) SSTEP(3, b2.w, c2.w)
        cA[n] = p; cX[n] = h; }
      { const int n = 3; const float Arn = Acur.w; float h = 0.f, p = 1.f;
        SSTEP(0, b3.x, c3.x) SSTEP(1, b3.y, c3.y) SSTEP(2, b3.z, c3.z) SSTEP(3, b3.w, c3.w)
        cA[n] = p; cX[n] = h; }
    }

    // ---- Wave-level scan on chunk aggregates — raw DPP, 2 inst/state/step.
    {
      float x0=cX[0], x1=cX[1], x2=cX[2], x3=cX[3];
      float a0_=cA[0], a1_=cA[1], a2_=cA[2], a3_=cA[3];
      asm("s_nop 1\n\t"
          SCAN_STEP("row_shr:1 row_mask:0xf bank_mask:0xf")
          SCAN_STEP("row_shr:2 row_mask:0xf bank_mask:0xf")
          SCAN_STEP("row_shr:4 row_mask:0xf bank_mask:0xf")
          SCAN_STEP("row_shr:8 row_mask:0xf bank_mask:0xf")
          SCAN_STEP("row_bcast:15 row_mask:0xa bank_mask:0xf")
          SCAN_STEP("row_bcast:31 row_mask:0xc bank_mask:0xf")
          : "+v"(x0), "+v"(x1), "+v"(x2), "+v"(x3),
            "+v"(a0_), "+v"(a1_), "+v"(a2_), "+v"(a3_));
      cX[0]=x0; cX[1]=x1; cX[2]=x2; cX[3]=x3;
      cA[0]=a0_; cA[1]=a1_; cA[2]=a2_; cA[3]=a3_;
    }

    // ---- Publish wave totals (lane 63 holds them).
    if (lane == 63) {
      #pragma unroll
      for (int n = 0; n < NQ; ++n) sAX[q][wid][n] = make_float2(cA[n], cX[n]);
    }

    // ---- Barrier WITHOUT vmcnt drain (raw s_barrier): lgkmcnt(0) makes the
    // sAX publish visible; the staging DMAs (vm-counted) stay in flight.
    __builtin_amdgcn_s_waitcnt(WAIT_LGKM0);
    __builtin_amdgcn_s_barrier();

    // ---- Parallel exclusive fold: all 7 candidate aggregates load
    // concurrently (one lgkm wait; 4-lane-group same-address broadcast =
    // conflict-free), then an identity-padded select+fma chain. wid is
    // wave-uniform. ex = x[wid-1] + a[wid-1]*(x[wid-2] + ...).
    float ex = 0.0f;                     // lane n<4: exclusive x-prefix, state n
    {
      const int n = lane & (NQ - 1);
      float2 s[NW - 1];
      #pragma unroll
      for (int w2 = 0; w2 < NW - 1; ++w2) s[w2] = sAX[q][w2][n];
      #pragma unroll
      for (int w2 = 0; w2 < NW - 1; ++w2) {
        float aa = (w2 < wid) ? s[w2].x : 1.0f;
        float xx = (w2 < wid) ? s[w2].y : 0.0f;
        ex = aa * ex + xx;
      }
    }

    // ---- Apply: y_i += cp_i * h0   (pure FMA; exn broadcast via readlane)
    #pragma unroll
    for (int n = 0; n < NQ; ++n) {
      float al = dppf<0x138,0xF>(1.0f, cA[n]);   // lane-exclusive prefix
      float xl = dppf<0x138,0xF>(0.0f, cX[n]);
      float exn = readlane_f(ex, n);             // scalar: wave-exclusive x
      float h0 = al * exn + xl;                  // state entering this chunk
      #pragma unroll
      for (int i = 0; i < T; ++i) y[i] += cp[n][i] * h0;
    }

    Acur = An;                           // A pipeline advance (4 v_movs)
    // no end-of-pass barrier: each pass uses its own sAX buffer; stg reuse is
    // safe within-wave (reads retired before next DMA lands).
  }

  // ---- Epilogue: + u*D, * silu(z), store  (u re-loaded here)
  const float Dd = Dv[d];
  const float4* z4 = reinterpret_cast<const float4*>(zm + roff);
  float4 z0 = z4[tid];
  float4 ua = u4[tid];
  float zv[T] = {z0.x, z0.y, z0.z, z0.w};
  float uv[T] = {ua.x, ua.y, ua.z, ua.w};
  float ov[T];
  #pragma unroll
  for (int i = 0; i < T; ++i) {
    float yy  = y[i] + uv[i] * Dd;
    float sig = 1.0f / (1.0f + fast_exp(-zv[i]));
    ov[i] = yy * zv[i] * sig;
  }
  reinterpret_cast<float4*>(out + roff)[tid] = make_float4(ov[0], ov[1], ov[2], ov[3]);
}

extern "C" void kernel_launch(void* const* d_in, const int* in_sizes, int n_in,
                              void* d_out, int out_size, void* d_ws, size_t ws_size,
                              hipStream_t stream)
{
  const float* u  = (const float*)d_in[0];
  const float* dl = (const float*)d_in[1];
  const float* A  = (const float*)d_in[2];
  const float* Bm = (const float*)d_in[3];
  const float* Cm = (const float*)d_in[4];
  const float* Dv = (const float*)d_in[5];
  const float* zm = (const float*)d_in[6];
  float* out = (float*)d_out;
  const int rows = in_sizes[0] / kL;   // b*d = 2048
  selscan_kernel<<<rows, BLOCK, 0, stream>>>(u, dl, A, Bm, Cm, Dv, zm, out);
}